// Round 14
// baseline (169.778 us; speedup 1.0000x reference)
//
#include <hip/hip_runtime.h>
#include <math.h>

#define B_ 256
#define S_ 50
#define K_ 20
#define D_ 128
#define G3 384          // 3*D
#define M_  (B_ * S_)   // 12800 (b,s) rows
#define GROWS 16        // batch rows per GRU block
#define NT 3            // n-tiles (16 wide) per wave: 8 waves x 48 = 384
#define KT 4            // k-tiles (32 wide): 128

typedef __attribute__((ext_vector_type(8))) short bf16x8;
typedef __attribute__((ext_vector_type(4))) float f32x4;

__device__ inline unsigned short bf16_rne(float f) {
    unsigned u = __float_as_uint(f);
    return (unsigned short)((u + 0x7fffu + ((u >> 16) & 1u)) >> 16);
}
__device__ inline float bf16f(unsigned short s) {
    return __uint_as_float(((unsigned)s) << 16);
}

// ---------------------------------------------------------------------------
// Kernel P: basket pooling. 256 thr/block = two (b,s) rows; 6400 blocks.
// ---------------------------------------------------------------------------
__global__ __launch_bounds__(256) void pool_kernel(
    const int* __restrict__ items, const int* __restrict__ basket_len,
    const int* __restrict__ lengths, const float* __restrict__ encode,
    float* __restrict__ pooled)
{
    const int tid  = threadIdx.x;
    const int pair = tid >> 7;
    const int d    = tid & 127;
    const int m    = blockIdx.x * 2 + pair;
    const int b    = m / S_;
    const int s    = m % S_;
    const int len  = lengths[b];

    float p = 0.f;
    if (s < len) {
        const int  blen = basket_len[m];
        const int* it   = items + m * K_;
        for (int k = 0; k < blen; ++k)
            p += encode[(long)it[k] * D_ + d];
        p /= (float)blen;
    }
    pooled[m * D_ + d] = p;
}

// ---------------------------------------------------------------------------
// Kernel G: gx = pooled @ w_ih^T + b_ih. M=12800, N=384, K=128.
// ---------------------------------------------------------------------------
__global__ __launch_bounds__(256) void gx_gemm_kernel(
    const float* __restrict__ pooled, const float* __restrict__ w_ih,
    const float* __restrict__ b_ih, float* __restrict__ gx)
{
    __shared__ float As[32][64];    // [k][m]
    __shared__ float Bs[32][128];   // [k][n]

    const int tid = threadIdx.x;
    const int bm  = blockIdx.x % 200;
    const int bn  = blockIdx.x / 200;
    const int m0  = bm * 64;
    const int n0  = bn * 128;
    const int tx  = tid & 15;               // -> N
    const int ty  = tid >> 4;               // -> M

    float acc[4][8] = {};

    for (int kt = 0; kt < 128; kt += 32) {
        #pragma unroll
        for (int i = 0; i < 2; ++i) {
            int idx = tid + 256 * i;
            int r = idx >> 3, c = idx & 7;
            float4 v = *reinterpret_cast<const float4*>(
                pooled + (m0 + r) * 128 + kt + c * 4);
            As[c*4+0][r] = v.x; As[c*4+1][r] = v.y;
            As[c*4+2][r] = v.z; As[c*4+3][r] = v.w;
        }
        #pragma unroll
        for (int i = 0; i < 4; ++i) {
            int idx = tid + 256 * i;
            int r = idx >> 3, c = idx & 7;
            float4 v = *reinterpret_cast<const float4*>(
                w_ih + (n0 + r) * 128 + kt + c * 4);
            Bs[c*4+0][r] = v.x; Bs[c*4+1][r] = v.y;
            Bs[c*4+2][r] = v.z; Bs[c*4+3][r] = v.w;
        }
        __syncthreads();

        #pragma unroll
        for (int k = 0; k < 32; ++k) {
            float4 a  = *reinterpret_cast<const float4*>(&As[k][ty * 4]);
            float4 b0 = *reinterpret_cast<const float4*>(&Bs[k][tx * 8]);
            float4 b1 = *reinterpret_cast<const float4*>(&Bs[k][tx * 8 + 4]);
            float av[4] = {a.x, a.y, a.z, a.w};
            float bv[8] = {b0.x, b0.y, b0.z, b0.w, b1.x, b1.y, b1.z, b1.w};
            #pragma unroll
            for (int mi = 0; mi < 4; ++mi)
                #pragma unroll
                for (int ni = 0; ni < 8; ++ni)
                    acc[mi][ni] = fmaf(av[mi], bv[ni], acc[mi][ni]);
        }
        __syncthreads();
    }

    float bias[8];
    #pragma unroll
    for (int ni = 0; ni < 8; ++ni) bias[ni] = b_ih[n0 + tx * 8 + ni];
    #pragma unroll
    for (int mi = 0; mi < 4; ++mi) {
        const int row = m0 + ty * 4 + mi;
        float4 o0, o1;
        o0.x = acc[mi][0] + bias[0]; o0.y = acc[mi][1] + bias[1];
        o0.z = acc[mi][2] + bias[2]; o0.w = acc[mi][3] + bias[3];
        o1.x = acc[mi][4] + bias[4]; o1.y = acc[mi][5] + bias[5];
        o1.z = acc[mi][6] + bias[6]; o1.w = acc[mi][7] + bias[7];
        float* dst = gx + (long)row * G3 + n0 + tx * 8;
        *reinterpret_cast<float4*>(dst)     = o0;
        *reinterpret_cast<float4*>(dst + 4) = o1;
    }
}

// ---------------------------------------------------------------------------
// Kernel B v5: MFMA GRU. 16 blocks x 512 thr (8 waves). Whole w_hh lives in
// MFMA B-fragments (hi/lo bf16, 96 VGPR/lane) loaded ONCE — kills the 2.5 GB
// per-step L2 weight broadcast (R12: L2-BW model 73us == measured 72.8us).
// Per step: gh(16x384) = mfma(h, w) with bf16 hi/lo split (~f32 precision),
// gh -> LDS, gate phase updates f32 h + swizzled bf16 hi/lo copies.
// Layouts (m89/m97): A lane: m=l&15, k=(l>>4)*8+j (contiguous 8);
// B lane: n=l&15, same k; C/D: col=l&15, row=(l>>4)*4+reg.
// ---------------------------------------------------------------------------
__global__ __launch_bounds__(512, 2) void gru_mfma_kernel(
    const int* __restrict__ lengths, const float* __restrict__ w_hh,
    const float* __restrict__ b_hh, const float* __restrict__ h0,
    const float* __restrict__ gx, float* __restrict__ out)
{
    const int b0   = blockIdx.x * GROWS;
    const int tid  = threadIdx.x;
    const int lane = tid & 63;
    const int wv   = tid >> 6;          // 0..7
    const int frow = lane & 15;         // m (A) / n (B) within tile
    const int fhi  = lane >> 4;         // 0..3 k-group

    __shared__ float          hf[GROWS][D_];       // master h (f32)
    __shared__ unsigned short hbh[GROWS * D_];     // h hi bf16, swizzled
    __shared__ unsigned short hbl[GROWS * D_];     // h lo bf16, swizzled
    __shared__ float          ghl[GROWS][G3];      // gh handoff

    // ---- weight fragments, loaded once (hi/lo bf16) ----
    bf16x8 wfh[NT][KT], wfl[NT][KT];
    #pragma unroll
    for (int nt = 0; nt < NT; ++nt) {
        #pragma unroll
        for (int kt = 0; kt < KT; ++kt) {
            const float* wp = w_hh + (wv*48 + nt*16 + frow) * D_ + kt*32 + fhi*8;
            bf16x8 vh, vl;
            #pragma unroll
            for (int j = 0; j < 8; ++j) {
                float f = wp[j];
                unsigned short h16 = bf16_rne(f);
                vh[j] = (short)h16;
                vl[j] = (short)bf16_rne(f - bf16f(h16));
            }
            wfh[nt][kt] = vh; wfl[nt][kt] = vl;
        }
    }

    // gate-phase mapping: thread -> (row gm, 4 dims at gd)
    const int gm = tid >> 5;            // 0..15
    const int gd = (tid & 31) * 4;      // 0..124
    const int mylen  = lengths[b0 + gm];
    const int lenmax = lengths[b0];     // lengths sorted descending

    {   // init h from h0
        float4 h00 = *(const float4*)(h0 + (long)(b0 + gm) * D_ + gd);
        *(float4*)&hf[gm][gd] = h00;
        int wb = (gm*256 + gd*2) ^ ((gm & 7) << 4);
        ushort4 uh, ul;
        uh.x = bf16_rne(h00.x); ul.x = bf16_rne(h00.x - bf16f(uh.x));
        uh.y = bf16_rne(h00.y); ul.y = bf16_rne(h00.y - bf16f(uh.y));
        uh.z = bf16_rne(h00.z); ul.z = bf16_rne(h00.z - bf16f(uh.z));
        uh.w = bf16_rne(h00.w); ul.w = bf16_rne(h00.w - bf16f(uh.w));
        *(ushort4*)((char*)hbh + wb) = uh;
        *(ushort4*)((char*)hbl + wb) = ul;
    }
    __syncthreads();

    float* ys = out;
    float* hu = out + (long)B_ * S_ * D_;

    for (int s = 0; s < lenmax; ++s) {
        // ---- A-fragments of h (hi/lo) from swizzled LDS ----
        bf16x8 ah[KT], al[KT];
        #pragma unroll
        for (int kt = 0; kt < KT; ++kt) {
            int ab = (frow*256 + kt*64 + fhi*16) ^ ((frow & 7) << 4);
            ah[kt] = *(const bf16x8*)((const char*)hbh + ab);
            al[kt] = *(const bf16x8*)((const char*)hbl + ab);
        }
        // ---- MFMA: gh = h @ w^T  (hi*hi + hi*lo + lo*hi) ----
        #pragma unroll
        for (int nt = 0; nt < NT; ++nt) {
            f32x4 c = {0.f, 0.f, 0.f, 0.f};
            #pragma unroll
            for (int kt = 0; kt < KT; ++kt) {
                c = __builtin_amdgcn_mfma_f32_16x16x32_bf16(al[kt], wfh[nt][kt], c, 0, 0, 0);
                c = __builtin_amdgcn_mfma_f32_16x16x32_bf16(ah[kt], wfl[nt][kt], c, 0, 0, 0);
                c = __builtin_amdgcn_mfma_f32_16x16x32_bf16(ah[kt], wfh[nt][kt], c, 0, 0, 0);
            }
            #pragma unroll
            for (int r = 0; r < 4; ++r)
                ghl[fhi*4 + r][wv*48 + nt*16 + frow] = c[r];
        }
        __syncthreads();

        // ---- gate phase ----
        const bool active = s < mylen;
        const float* gxp = gx + ((long)(b0 + gm) * S_ + s) * G3 + gd;
        float4 gxr = *(const float4*)(gxp);
        float4 gxz = *(const float4*)(gxp + 128);
        float4 gxn = *(const float4*)(gxp + 256);
        float4 ghr = *(const float4*)&ghl[gm][gd];
        float4 ghz = *(const float4*)&ghl[gm][128 + gd];
        float4 ghn = *(const float4*)&ghl[gm][256 + gd];
        float4 bhr = *(const float4*)(b_hh + gd);
        float4 bhz = *(const float4*)(b_hh + 128 + gd);
        float4 bhn = *(const float4*)(b_hh + 256 + gd);
        float4 hp  = *(float4*)&hf[gm][gd];
        float4 hn4;
        #define GATE(c) { \
            float r = 1.f / (1.f + expf(-(gxr.c + ghr.c + bhr.c))); \
            float z = 1.f / (1.f + expf(-(gxz.c + ghz.c + bhz.c))); \
            float n = tanhf(gxn.c + r * (ghn.c + bhn.c)); \
            hn4.c = (1.f - z) * n + z * hp.c; }
        GATE(x) GATE(y) GATE(z) GATE(w)
        #undef GATE
        if (active) {
            *(float4*)(ys + ((long)(b0 + gm) * S_ + s) * D_ + gd) = hn4;
            *(float4*)&hf[gm][gd] = hn4;
            int wb = (gm*256 + gd*2) ^ ((gm & 7) << 4);
            ushort4 uh, ul;
            uh.x = bf16_rne(hn4.x); ul.x = bf16_rne(hn4.x - bf16f(uh.x));
            uh.y = bf16_rne(hn4.y); ul.y = bf16_rne(hn4.y - bf16f(uh.y));
            uh.z = bf16_rne(hn4.z); ul.z = bf16_rne(hn4.z - bf16f(uh.z));
            uh.w = bf16_rne(hn4.w); ul.w = bf16_rne(hn4.w - bf16f(uh.w));
            *(ushort4*)((char*)hbh + wb) = uh;
            *(ushort4*)((char*)hbl + wb) = ul;
        }
        __syncthreads();
    }

    // final hidden + zero tail
    *(float4*)(hu + (long)(b0 + gm) * D_ + gd) = *(float4*)&hf[gm][gd];
    float4 zz = {0.f, 0.f, 0.f, 0.f};
    for (int s = mylen; s < S_; ++s)
        *(float4*)(ys + ((long)(b0 + gm) * S_ + s) * D_ + gd) = zz;
}

extern "C" void kernel_launch(void* const* d_in, const int* in_sizes, int n_in,
                              void* d_out, int out_size, void* d_ws, size_t ws_size,
                              hipStream_t stream) {
    const int*   items      = (const int*)d_in[0];
    const int*   basket_len = (const int*)d_in[1];
    const int*   lengths    = (const int*)d_in[2];
    const float* encode     = (const float*)d_in[3];
    const float* w_ih       = (const float*)d_in[4];
    const float* w_hh       = (const float*)d_in[5];
    const float* b_ih       = (const float*)d_in[6];
    const float* b_hh       = (const float*)d_in[7];
    const float* h0         = (const float*)d_in[8];
    float* out = (float*)d_out;

    float* gx     = (float*)d_ws;                       // 12800*384 f32 = 19.66 MB
    float* pooled = gx + (long)M_ * G3;                 // 12800*128 f32 =  6.55 MB

    pool_kernel<<<M_ / 2, 256, 0, stream>>>(
        items, basket_len, lengths, encode, pooled);
    gx_gemm_kernel<<<600, 256, 0, stream>>>(
        pooled, w_ih, b_ih, gx);
    gru_mfma_kernel<<<B_ / GROWS, 512, 0, stream>>>(
        lengths, w_hh, b_hh, h0, gx, out);
}

// Round 16
// 138.530 us; speedup vs baseline: 1.2256x; 1.2256x over previous
//
#include <hip/hip_runtime.h>
#include <math.h>

#define B_ 256
#define S_ 50
#define K_ 20
#define D_ 128
#define G3 384          // 3*D
#define G3P 400         // padded ghl stride: 400 % 32 == 16 -> 2-way (free)
#define M_  (B_ * S_)   // 12800 (b,s) rows
#define GROWS 16        // batch rows per GRU block
#define NT 3            // n-tiles (16 wide) per wave: 8 waves x 48 = 384
#define KT 4            // k-tiles (32 wide): 128

typedef __attribute__((ext_vector_type(8))) short bf16x8;
typedef __attribute__((ext_vector_type(4))) float f32x4;

__device__ inline unsigned short bf16_rne(float f) {
    unsigned u = __float_as_uint(f);
    return (unsigned short)((u + 0x7fffu + ((u >> 16) & 1u)) >> 16);
}
__device__ inline float fsig(float x) {           // sigmoid via v_exp
    return 1.f / (1.f + __expf(-x));
}
__device__ inline float ftanh(float x) {          // saturation-safe tanh
    float t = __expf(-2.f * fabsf(x));            // t in (0,1]
    float r = (1.f - t) / (1.f + t);
    return x >= 0.f ? r : -r;
}

// ---------------------------------------------------------------------------
// Kernel P: basket pooling. 256 thr/block = two (b,s) rows; 6400 blocks.
// ---------------------------------------------------------------------------
__global__ __launch_bounds__(256) void pool_kernel(
    const int* __restrict__ items, const int* __restrict__ basket_len,
    const int* __restrict__ lengths, const float* __restrict__ encode,
    float* __restrict__ pooled)
{
    const int tid  = threadIdx.x;
    const int pair = tid >> 7;
    const int d    = tid & 127;
    const int m    = blockIdx.x * 2 + pair;
    const int b    = m / S_;
    const int s    = m % S_;
    const int len  = lengths[b];

    float p = 0.f;
    if (s < len) {
        const int  blen = basket_len[m];
        const int* it   = items + m * K_;
        for (int k = 0; k < blen; ++k)
            p += encode[(long)it[k] * D_ + d];
        p /= (float)blen;
    }
    pooled[m * D_ + d] = p;
}

// ---------------------------------------------------------------------------
// Kernel G: gx = pooled @ w_ih^T + b_ih (+ b_hh folded ONLY for r/z thirds).
// R15 failure: folding b_hh for the n-third is wrong — reference has
// n = tanh(gx_n + r*(gh_n + b_hh_n)); b_hh_n must stay inside the r-multiply.
// ---------------------------------------------------------------------------
__global__ __launch_bounds__(256) void gx_gemm_kernel(
    const float* __restrict__ pooled, const float* __restrict__ w_ih,
    const float* __restrict__ b_ih, const float* __restrict__ b_hh,
    float* __restrict__ gx)
{
    __shared__ float As[32][64];    // [k][m]
    __shared__ float Bs[32][128];   // [k][n]

    const int tid = threadIdx.x;
    const int bm  = blockIdx.x % 200;
    const int bn  = blockIdx.x / 200;
    const int m0  = bm * 64;
    const int n0  = bn * 128;
    const int tx  = tid & 15;               // -> N
    const int ty  = tid >> 4;               // -> M

    float acc[4][8] = {};

    for (int kt = 0; kt < 128; kt += 32) {
        #pragma unroll
        for (int i = 0; i < 2; ++i) {
            int idx = tid + 256 * i;
            int r = idx >> 3, c = idx & 7;
            float4 v = *reinterpret_cast<const float4*>(
                pooled + (m0 + r) * 128 + kt + c * 4);
            As[c*4+0][r] = v.x; As[c*4+1][r] = v.y;
            As[c*4+2][r] = v.z; As[c*4+3][r] = v.w;
        }
        #pragma unroll
        for (int i = 0; i < 4; ++i) {
            int idx = tid + 256 * i;
            int r = idx >> 3, c = idx & 7;
            float4 v = *reinterpret_cast<const float4*>(
                w_ih + (n0 + r) * 128 + kt + c * 4);
            Bs[c*4+0][r] = v.x; Bs[c*4+1][r] = v.y;
            Bs[c*4+2][r] = v.z; Bs[c*4+3][r] = v.w;
        }
        __syncthreads();

        #pragma unroll
        for (int k = 0; k < 32; ++k) {
            float4 a  = *reinterpret_cast<const float4*>(&As[k][ty * 4]);
            float4 b0 = *reinterpret_cast<const float4*>(&Bs[k][tx * 8]);
            float4 b1 = *reinterpret_cast<const float4*>(&Bs[k][tx * 8 + 4]);
            float av[4] = {a.x, a.y, a.z, a.w};
            float bv[8] = {b0.x, b0.y, b0.z, b0.w, b1.x, b1.y, b1.z, b1.w};
            #pragma unroll
            for (int mi = 0; mi < 4; ++mi)
                #pragma unroll
                for (int ni = 0; ni < 8; ++ni)
                    acc[mi][ni] = fmaf(av[mi], bv[ni], acc[mi][ni]);
        }
        __syncthreads();
    }

    float bias[8];
    #pragma unroll
    for (int ni = 0; ni < 8; ++ni) {
        int n = n0 + tx * 8 + ni;
        bias[ni] = b_ih[n] + (n < 2 * D_ ? b_hh[n] : 0.f);   // fold r/z only
    }
    #pragma unroll
    for (int mi = 0; mi < 4; ++mi) {
        const int row = m0 + ty * 4 + mi;
        float4 o0, o1;
        o0.x = acc[mi][0] + bias[0]; o0.y = acc[mi][1] + bias[1];
        o0.z = acc[mi][2] + bias[2]; o0.w = acc[mi][3] + bias[3];
        o1.x = acc[mi][4] + bias[4]; o1.y = acc[mi][5] + bias[5];
        o1.z = acc[mi][6] + bias[6]; o1.w = acc[mi][7] + bias[7];
        float* dst = gx + (long)row * G3 + n0 + tx * 8;
        *reinterpret_cast<float4*>(dst)     = o0;
        *reinterpret_cast<float4*>(dst + 4) = o1;
    }
}

// ---------------------------------------------------------------------------
// Kernel B v7: MFMA GRU, single-bf16, n-gate bias INSIDE the r-multiply
// (bhn hoisted to a loop-invariant register float4). Otherwise v6:
// fragments resident, fast gates, gx prefetch, padded ghl.
// ---------------------------------------------------------------------------
__global__ __launch_bounds__(512, 2) void gru_mfma_kernel(
    const int* __restrict__ lengths, const float* __restrict__ w_hh,
    const float* __restrict__ b_hh, const float* __restrict__ h0,
    const float* __restrict__ gx, float* __restrict__ out)
{
    const int b0   = blockIdx.x * GROWS;
    const int tid  = threadIdx.x;
    const int lane = tid & 63;
    const int wv   = tid >> 6;          // 0..7
    const int frow = lane & 15;         // m (A) / n (B) within tile
    const int fhi  = lane >> 4;         // 0..3 k-group

    __shared__ float          hf[GROWS][D_];       // master h (f32)
    __shared__ unsigned short hbh[GROWS * D_];     // h bf16, swizzled
    __shared__ float          ghl[GROWS][G3P];     // gh handoff (padded)

    // ---- weight fragments, loaded once (bf16) ----
    bf16x8 wf[NT][KT];
    #pragma unroll
    for (int nt = 0; nt < NT; ++nt) {
        #pragma unroll
        for (int kt = 0; kt < KT; ++kt) {
            const float* wp = w_hh + (wv*48 + nt*16 + frow) * D_ + kt*32 + fhi*8;
            bf16x8 vh;
            #pragma unroll
            for (int j = 0; j < 8; ++j) vh[j] = (short)bf16_rne(wp[j]);
            wf[nt][kt] = vh;
        }
    }

    // gate-phase mapping: thread -> (row gm, 4 dims at gd)
    const int gm = tid >> 5;            // 0..15
    const int gd = (tid & 31) * 4;      // 0..124
    const int mylen  = lengths[b0 + gm];
    const int lenmax = lengths[b0];     // lengths sorted descending

    // loop-invariant n-gate bias (reference: n = tanh(gxn + r*(ghn + bhn)))
    const float4 bhn = *(const float4*)(b_hh + 2 * D_ + gd);

    {   // init h from h0
        float4 h00 = *(const float4*)(h0 + (long)(b0 + gm) * D_ + gd);
        *(float4*)&hf[gm][gd] = h00;
        int wb = (gm*256 + gd*2) ^ ((gm & 7) << 4);
        ushort4 uh;
        uh.x = bf16_rne(h00.x); uh.y = bf16_rne(h00.y);
        uh.z = bf16_rne(h00.z); uh.w = bf16_rne(h00.w);
        *(ushort4*)((char*)hbh + wb) = uh;
    }
    __syncthreads();

    float* ys = out;
    float* hu = out + (long)B_ * S_ * D_;

    for (int s = 0; s < lenmax; ++s) {
        // ---- prefetch gx (read-only, no dep on h) — covered by MFMA phase ----
        const float* gxp = gx + ((long)(b0 + gm) * S_ + s) * G3 + gd;
        float4 gxr = *(const float4*)(gxp);
        float4 gxz = *(const float4*)(gxp + 128);
        float4 gxn = *(const float4*)(gxp + 256);

        // ---- A-fragments of h from swizzled LDS (2-way = free) ----
        bf16x8 ah[KT];
        #pragma unroll
        for (int kt = 0; kt < KT; ++kt) {
            int ab = (frow*256 + kt*64 + fhi*16) ^ ((frow & 7) << 4);
            ah[kt] = *(const bf16x8*)((const char*)hbh + ab);
        }
        // ---- MFMA: gh = h @ w^T, 3 independent 4-chains ----
        #pragma unroll
        for (int nt = 0; nt < NT; ++nt) {
            f32x4 c = {0.f, 0.f, 0.f, 0.f};
            #pragma unroll
            for (int kt = 0; kt < KT; ++kt)
                c = __builtin_amdgcn_mfma_f32_16x16x32_bf16(ah[kt], wf[nt][kt], c, 0, 0, 0);
            #pragma unroll
            for (int r = 0; r < 4; ++r)
                ghl[fhi*4 + r][wv*48 + nt*16 + frow] = c[r];
        }
        __syncthreads();

        // ---- gate phase ----
        const bool active = s < mylen;
        float4 ghr = *(const float4*)&ghl[gm][gd];
        float4 ghz = *(const float4*)&ghl[gm][128 + gd];
        float4 ghn = *(const float4*)&ghl[gm][256 + gd];
        float4 hp  = *(float4*)&hf[gm][gd];
        float4 hn4;
        #define GATE(c) { \
            float r = fsig(gxr.c + ghr.c); \
            float z = fsig(gxz.c + ghz.c); \
            float n = ftanh(gxn.c + r * (ghn.c + bhn.c)); \
            hn4.c = (1.f - z) * n + z * hp.c; }
        GATE(x) GATE(y) GATE(z) GATE(w)
        #undef GATE
        if (active) {
            *(float4*)(ys + ((long)(b0 + gm) * S_ + s) * D_ + gd) = hn4;
            *(float4*)&hf[gm][gd] = hn4;
            int wb = (gm*256 + gd*2) ^ ((gm & 7) << 4);
            ushort4 uh;
            uh.x = bf16_rne(hn4.x); uh.y = bf16_rne(hn4.y);
            uh.z = bf16_rne(hn4.z); uh.w = bf16_rne(hn4.w);
            *(ushort4*)((char*)hbh + wb) = uh;
        }
        __syncthreads();
    }

    // final hidden + zero tail
    *(float4*)(hu + (long)(b0 + gm) * D_ + gd) = *(float4*)&hf[gm][gd];
    float4 zz = {0.f, 0.f, 0.f, 0.f};
    for (int s = mylen; s < S_; ++s)
        *(float4*)(ys + ((long)(b0 + gm) * S_ + s) * D_ + gd) = zz;
}

extern "C" void kernel_launch(void* const* d_in, const int* in_sizes, int n_in,
                              void* d_out, int out_size, void* d_ws, size_t ws_size,
                              hipStream_t stream) {
    const int*   items      = (const int*)d_in[0];
    const int*   basket_len = (const int*)d_in[1];
    const int*   lengths    = (const int*)d_in[2];
    const float* encode     = (const float*)d_in[3];
    const float* w_ih       = (const float*)d_in[4];
    const float* w_hh       = (const float*)d_in[5];
    const float* b_ih       = (const float*)d_in[6];
    const float* b_hh       = (const float*)d_in[7];
    const float* h0         = (const float*)d_in[8];
    float* out = (float*)d_out;

    float* gx     = (float*)d_ws;                       // 12800*384 f32 = 19.66 MB
    float* pooled = gx + (long)M_ * G3;                 // 12800*128 f32 =  6.55 MB

    pool_kernel<<<M_ / 2, 256, 0, stream>>>(
        items, basket_len, lengths, encode, pooled);
    gx_gemm_kernel<<<600, 256, 0, stream>>>(
        pooled, w_ih, b_ih, b_hh, gx);
    gru_mfma_kernel<<<B_ / GROWS, 512, 0, stream>>>(
        lengths, w_hh, b_hh, h0, gx, out);
}

// Round 17
// 129.859 us; speedup vs baseline: 1.3074x; 1.0668x over previous
//
#include <hip/hip_runtime.h>
#include <math.h>

#define B_ 256
#define S_ 50
#define K_ 20
#define D_ 128
#define G3 384          // 3*D
#define M_  (B_ * S_)   // 12800 (b,s) rows
#define GROWS 16        // batch rows per GRU block
#define KT 4            // k-tiles (32 wide): 128

typedef __attribute__((ext_vector_type(8))) short bf16x8;
typedef __attribute__((ext_vector_type(4))) float f32x4;

__device__ inline unsigned short bf16_rne(float f) {
    unsigned u = __float_as_uint(f);
    return (unsigned short)((u + 0x7fffu + ((u >> 16) & 1u)) >> 16);
}
__device__ inline float fsig(float x) {
    return 1.f / (1.f + __expf(-x));
}
__device__ inline float ftanh(float x) {
    float t = __expf(-2.f * fabsf(x));
    float r = (1.f - t) / (1.f + t);
    return x >= 0.f ? r : -r;
}

// ---------------------------------------------------------------------------
// Kernel P: basket pooling. 256 thr/block = two (b,s) rows; 6400 blocks.
// ---------------------------------------------------------------------------
__global__ __launch_bounds__(256) void pool_kernel(
    const int* __restrict__ items, const int* __restrict__ basket_len,
    const int* __restrict__ lengths, const float* __restrict__ encode,
    float* __restrict__ pooled)
{
    const int tid  = threadIdx.x;
    const int pair = tid >> 7;
    const int d    = tid & 127;
    const int m    = blockIdx.x * 2 + pair;
    const int b    = m / S_;
    const int s    = m % S_;
    const int len  = lengths[b];

    float p = 0.f;
    if (s < len) {
        const int  blen = basket_len[m];
        const int* it   = items + m * K_;
        for (int k = 0; k < blen; ++k)
            p += encode[(long)it[k] * D_ + d];
        p /= (float)blen;
    }
    pooled[m * D_ + d] = p;
}

// ---------------------------------------------------------------------------
// Kernel G: gx = pooled @ w_ih^T + b_ih (+ b_hh folded ONLY for r/z thirds).
// ---------------------------------------------------------------------------
__global__ __launch_bounds__(256) void gx_gemm_kernel(
    const float* __restrict__ pooled, const float* __restrict__ w_ih,
    const float* __restrict__ b_ih, const float* __restrict__ b_hh,
    float* __restrict__ gx)
{
    __shared__ float As[32][64];    // [k][m]
    __shared__ float Bs[32][128];   // [k][n]

    const int tid = threadIdx.x;
    const int bm  = blockIdx.x % 200;
    const int bn  = blockIdx.x / 200;
    const int m0  = bm * 64;
    const int n0  = bn * 128;
    const int tx  = tid & 15;               // -> N
    const int ty  = tid >> 4;               // -> M

    float acc[4][8] = {};

    for (int kt = 0; kt < 128; kt += 32) {
        #pragma unroll
        for (int i = 0; i < 2; ++i) {
            int idx = tid + 256 * i;
            int r = idx >> 3, c = idx & 7;
            float4 v = *reinterpret_cast<const float4*>(
                pooled + (m0 + r) * 128 + kt + c * 4);
            As[c*4+0][r] = v.x; As[c*4+1][r] = v.y;
            As[c*4+2][r] = v.z; As[c*4+3][r] = v.w;
        }
        #pragma unroll
        for (int i = 0; i < 4; ++i) {
            int idx = tid + 256 * i;
            int r = idx >> 3, c = idx & 7;
            float4 v = *reinterpret_cast<const float4*>(
                w_ih + (n0 + r) * 128 + kt + c * 4);
            Bs[c*4+0][r] = v.x; Bs[c*4+1][r] = v.y;
            Bs[c*4+2][r] = v.z; Bs[c*4+3][r] = v.w;
        }
        __syncthreads();

        #pragma unroll
        for (int k = 0; k < 32; ++k) {
            float4 a  = *reinterpret_cast<const float4*>(&As[k][ty * 4]);
            float4 b0 = *reinterpret_cast<const float4*>(&Bs[k][tx * 8]);
            float4 b1 = *reinterpret_cast<const float4*>(&Bs[k][tx * 8 + 4]);
            float av[4] = {a.x, a.y, a.z, a.w};
            float bv[8] = {b0.x, b0.y, b0.z, b0.w, b1.x, b1.y, b1.z, b1.w};
            #pragma unroll
            for (int mi = 0; mi < 4; ++mi)
                #pragma unroll
                for (int ni = 0; ni < 8; ++ni)
                    acc[mi][ni] = fmaf(av[mi], bv[ni], acc[mi][ni]);
        }
        __syncthreads();
    }

    float bias[8];
    #pragma unroll
    for (int ni = 0; ni < 8; ++ni) {
        int n = n0 + tx * 8 + ni;
        bias[ni] = b_ih[n] + (n < 2 * D_ ? b_hh[n] : 0.f);   // fold r/z only
    }
    #pragma unroll
    for (int mi = 0; mi < 4; ++mi) {
        const int row = m0 + ty * 4 + mi;
        float4 o0, o1;
        o0.x = acc[mi][0] + bias[0]; o0.y = acc[mi][1] + bias[1];
        o0.z = acc[mi][2] + bias[2]; o0.w = acc[mi][3] + bias[3];
        o1.x = acc[mi][4] + bias[4]; o1.y = acc[mi][5] + bias[5];
        o1.z = acc[mi][6] + bias[6]; o1.w = acc[mi][7] + bias[7];
        float* dst = gx + (long)row * G3 + n0 + tx * 8;
        *reinterpret_cast<float4*>(dst)     = o0;
        *reinterpret_cast<float4*>(dst + 4) = o1;
    }
}

// ---------------------------------------------------------------------------
// Kernel B v8: MFMA GRU, gates-in-registers. Each wave owns 16 dims and
// computes the r,z,n tiles for those dims (B rows g*128 + wv*16+frow), so
// the C fragment (col=dim, row=batch) IS the gate input — no gh LDS buffer,
// hprev stays in the same lane across steps, ONE barrier/step (ping-pong h).
// gx software-pipelined one full step ahead (R16: same-step prefetch left
// ~700cyc HBM stall on the critical path -> 83.6us).
// ---------------------------------------------------------------------------
__global__ __launch_bounds__(512, 1) void gru_mfma_kernel(
    const int* __restrict__ lengths, const float* __restrict__ w_hh,
    const float* __restrict__ b_hh, const float* __restrict__ h0,
    const float* __restrict__ gx, float* __restrict__ out)
{
    const int b0   = blockIdx.x * GROWS;
    const int tid  = threadIdx.x;
    const int lane = tid & 63;
    const int wv   = tid >> 6;          // 0..7
    const int frow = lane & 15;         // fragment row: dim-within-16 (A: batch m)
    const int fhi  = lane >> 4;         // 0..3 k-group
    const int dim  = wv * 16 + frow;    // this lane's hidden dim (0..127)

    __shared__ unsigned short hb[2][GROWS * D_];   // bf16 h, ping-pong, swizzled

    // ---- weight fragments: gate g, B rows g*128 + (wv*16+frow), loaded once ----
    bf16x8 wf[3][KT];
    #pragma unroll
    for (int g = 0; g < 3; ++g) {
        #pragma unroll
        for (int kt = 0; kt < KT; ++kt) {
            const float* wp = w_hh + (g * D_ + dim) * D_ + kt * 32 + fhi * 8;
            bf16x8 v;
            #pragma unroll
            for (int j = 0; j < 8; ++j) v[j] = (short)bf16_rne(wp[j]);
            wf[g][kt] = v;
        }
    }

    const float bhn_s = b_hh[2 * D_ + dim];   // n-gate bias, one scalar/lane

    // gate rows this lane owns: fhi*4 + r
    int   mylen[4];
    float hp[4];
    #pragma unroll
    for (int r = 0; r < 4; ++r) {
        int row = fhi * 4 + r;
        mylen[r] = lengths[b0 + row];
        hp[r]    = h0[(long)(b0 + row) * D_ + dim];
        int wb = (row * 256 + dim * 2) ^ ((row & 7) << 4);
        *(unsigned short*)((char*)hb[0] + wb) = bf16_rne(hp[r]);
    }
    const int lenmax = lengths[b0];     // lengths sorted descending
    __syncthreads();

    float* ys = out;
    float* hu = out + (long)B_ * S_ * D_;

    // ---- gx pipeline: cur holds step-s values, nxt prefetches s+1 ----
    float cur[3][4], nxt[3][4];
    #pragma unroll
    for (int g = 0; g < 3; ++g)
        #pragma unroll
        for (int r = 0; r < 4; ++r)
            cur[g][r] = gx[((long)(b0 + fhi * 4 + r) * S_ + 0) * G3 + g * 128 + dim];

    int pp = 0;
    for (int s = 0; s < lenmax; ++s) {
        // prefetch gx for s+1 (consumed next iteration -> full step of cover)
        const int sn = (s + 1 < lenmax) ? s + 1 : lenmax - 1;
        #pragma unroll
        for (int g = 0; g < 3; ++g)
            #pragma unroll
            for (int r = 0; r < 4; ++r)
                nxt[g][r] = gx[((long)(b0 + fhi * 4 + r) * S_ + sn) * G3 + g * 128 + dim];

        // A-fragments of h (batch m = frow, k = kt*32 + fhi*8 + j), swizzled
        bf16x8 ah[KT];
        #pragma unroll
        for (int kt = 0; kt < KT; ++kt) {
            int ab = (frow * 256 + kt * 64 + fhi * 16) ^ ((frow & 7) << 4);
            ah[kt] = *(const bf16x8*)((const char*)hb[pp] + ab);
        }

        // 3 gate tiles: C col = dim (n-index), C row = batch (m-index)
        f32x4 cr = {0.f,0.f,0.f,0.f}, cz = {0.f,0.f,0.f,0.f}, cn = {0.f,0.f,0.f,0.f};
        #pragma unroll
        for (int kt = 0; kt < KT; ++kt) {
            cr = __builtin_amdgcn_mfma_f32_16x16x32_bf16(ah[kt], wf[0][kt], cr, 0, 0, 0);
            cz = __builtin_amdgcn_mfma_f32_16x16x32_bf16(ah[kt], wf[1][kt], cz, 0, 0, 0);
            cn = __builtin_amdgcn_mfma_f32_16x16x32_bf16(ah[kt], wf[2][kt], cn, 0, 0, 0);
        }

        // gates fully in registers; hprev in registers
        #pragma unroll
        for (int r = 0; r < 4; ++r) {
            const int row = fhi * 4 + r;
            const bool act = s < mylen[r];
            float rg = fsig(cur[0][r] + cr[r]);
            float zg = fsig(cur[1][r] + cz[r]);
            float ng = ftanh(cur[2][r] + rg * (cn[r] + bhn_s));
            float hn = (1.f - zg) * ng + zg * hp[r];
            if (act) {
                ys[((long)(b0 + row) * S_ + s) * D_ + dim] = hn;
                hp[r] = hn;
            }
            int wb = (row * 256 + dim * 2) ^ ((row & 7) << 4);
            *(unsigned short*)((char*)hb[pp ^ 1] + wb) = bf16_rne(hp[r]);
        }
        __syncthreads();
        pp ^= 1;
        #pragma unroll
        for (int g = 0; g < 3; ++g)
            #pragma unroll
            for (int r = 0; r < 4; ++r)
                cur[g][r] = nxt[g][r];
    }

    // final hidden + zero tails
    #pragma unroll
    for (int r = 0; r < 4; ++r) {
        const int row = fhi * 4 + r;
        hu[(long)(b0 + row) * D_ + dim] = hp[r];
        for (int s = mylen[r]; s < S_; ++s)
            ys[((long)(b0 + row) * S_ + s) * D_ + dim] = 0.f;
    }
}

extern "C" void kernel_launch(void* const* d_in, const int* in_sizes, int n_in,
                              void* d_out, int out_size, void* d_ws, size_t ws_size,
                              hipStream_t stream) {
    const int*   items      = (const int*)d_in[0];
    const int*   basket_len = (const int*)d_in[1];
    const int*   lengths    = (const int*)d_in[2];
    const float* encode     = (const float*)d_in[3];
    const float* w_ih       = (const float*)d_in[4];
    const float* w_hh       = (const float*)d_in[5];
    const float* b_ih       = (const float*)d_in[6];
    const float* b_hh       = (const float*)d_in[7];
    const float* h0         = (const float*)d_in[8];
    float* out = (float*)d_out;

    float* gx     = (float*)d_ws;                       // 12800*384 f32 = 19.66 MB
    float* pooled = gx + (long)M_ * G3;                 // 12800*128 f32 =  6.55 MB

    pool_kernel<<<M_ / 2, 256, 0, stream>>>(
        items, basket_len, lengths, encode, pooled);
    gx_gemm_kernel<<<600, 256, 0, stream>>>(
        pooled, w_ih, b_ih, b_hh, gx);
    gru_mfma_kernel<<<B_ / GROWS, 512, 0, stream>>>(
        lengths, w_hh, b_hh, h0, gx, out);
}

// Round 18
// 113.089 us; speedup vs baseline: 1.5013x; 1.1483x over previous
//
#include <hip/hip_runtime.h>
#include <math.h>

#define B_ 256
#define S_ 50
#define K_ 20
#define D_ 128
#define G3 384          // 3*D
#define M_  (B_ * S_)   // 12800 (b,s) rows
#define GROWS 16        // batch rows per GRU block
#define KT 4            // k-tiles (32 wide): 128

typedef __attribute__((ext_vector_type(8))) short bf16x8;
typedef __attribute__((ext_vector_type(4))) float f32x4;

__device__ inline unsigned short bf16_rne(float f) {
    unsigned u = __float_as_uint(f);
    return (unsigned short)((u + 0x7fffu + ((u >> 16) & 1u)) >> 16);
}
__device__ inline float fsig(float x) {           // sigmoid, v_rcp (1ulp)
    return __builtin_amdgcn_rcpf(1.f + __expf(-x));
}
__device__ inline float ftanh(float x) {          // saturation-safe tanh, v_rcp
    float t = __expf(-2.f * fabsf(x));
    float r = (1.f - t) * __builtin_amdgcn_rcpf(1.f + t);
    return x >= 0.f ? r : -r;
}

// LDS-only workgroup barrier: drains ds_writes (lgkmcnt) but leaves global
// loads/stores in flight across the barrier (R17: __syncthreads' vmcnt(0)
// drain nullified the gx software pipeline -> 3600cyc/step).
#define WG_SYNC_LDS() do { \
    __builtin_amdgcn_sched_barrier(0); \
    asm volatile("s_waitcnt lgkmcnt(0)" ::: "memory"); \
    __builtin_amdgcn_s_barrier(); \
    __builtin_amdgcn_sched_barrier(0); \
} while (0)

// ---------------------------------------------------------------------------
// Kernel P: basket pooling. 256 thr/block = two (b,s) rows; 6400 blocks.
// ---------------------------------------------------------------------------
__global__ __launch_bounds__(256) void pool_kernel(
    const int* __restrict__ items, const int* __restrict__ basket_len,
    const int* __restrict__ lengths, const float* __restrict__ encode,
    float* __restrict__ pooled)
{
    const int tid  = threadIdx.x;
    const int pair = tid >> 7;
    const int d    = tid & 127;
    const int m    = blockIdx.x * 2 + pair;
    const int b    = m / S_;
    const int s    = m % S_;
    const int len  = lengths[b];

    float p = 0.f;
    if (s < len) {
        const int  blen = basket_len[m];
        const int* it   = items + m * K_;
        for (int k = 0; k < blen; ++k)
            p += encode[(long)it[k] * D_ + d];
        p /= (float)blen;
    }
    pooled[m * D_ + d] = p;
}

// ---------------------------------------------------------------------------
// Kernel G: gx = pooled @ w_ih^T + b_ih (+ b_hh folded ONLY for r/z thirds).
// ---------------------------------------------------------------------------
__global__ __launch_bounds__(256) void gx_gemm_kernel(
    const float* __restrict__ pooled, const float* __restrict__ w_ih,
    const float* __restrict__ b_ih, const float* __restrict__ b_hh,
    float* __restrict__ gx)
{
    __shared__ float As[32][64];    // [k][m]
    __shared__ float Bs[32][128];   // [k][n]

    const int tid = threadIdx.x;
    const int bm  = blockIdx.x % 200;
    const int bn  = blockIdx.x / 200;
    const int m0  = bm * 64;
    const int n0  = bn * 128;
    const int tx  = tid & 15;               // -> N
    const int ty  = tid >> 4;               // -> M

    float acc[4][8] = {};

    for (int kt = 0; kt < 128; kt += 32) {
        #pragma unroll
        for (int i = 0; i < 2; ++i) {
            int idx = tid + 256 * i;
            int r = idx >> 3, c = idx & 7;
            float4 v = *reinterpret_cast<const float4*>(
                pooled + (m0 + r) * 128 + kt + c * 4);
            As[c*4+0][r] = v.x; As[c*4+1][r] = v.y;
            As[c*4+2][r] = v.z; As[c*4+3][r] = v.w;
        }
        #pragma unroll
        for (int i = 0; i < 4; ++i) {
            int idx = tid + 256 * i;
            int r = idx >> 3, c = idx & 7;
            float4 v = *reinterpret_cast<const float4*>(
                w_ih + (n0 + r) * 128 + kt + c * 4);
            Bs[c*4+0][r] = v.x; Bs[c*4+1][r] = v.y;
            Bs[c*4+2][r] = v.z; Bs[c*4+3][r] = v.w;
        }
        __syncthreads();

        #pragma unroll
        for (int k = 0; k < 32; ++k) {
            float4 a  = *reinterpret_cast<const float4*>(&As[k][ty * 4]);
            float4 b0 = *reinterpret_cast<const float4*>(&Bs[k][tx * 8]);
            float4 b1 = *reinterpret_cast<const float4*>(&Bs[k][tx * 8 + 4]);
            float av[4] = {a.x, a.y, a.z, a.w};
            float bv[8] = {b0.x, b0.y, b0.z, b0.w, b1.x, b1.y, b1.z, b1.w};
            #pragma unroll
            for (int mi = 0; mi < 4; ++mi)
                #pragma unroll
                for (int ni = 0; ni < 8; ++ni)
                    acc[mi][ni] = fmaf(av[mi], bv[ni], acc[mi][ni]);
        }
        __syncthreads();
    }

    float bias[8];
    #pragma unroll
    for (int ni = 0; ni < 8; ++ni) {
        int n = n0 + tx * 8 + ni;
        bias[ni] = b_ih[n] + (n < 2 * D_ ? b_hh[n] : 0.f);   // fold r/z only
    }
    #pragma unroll
    for (int mi = 0; mi < 4; ++mi) {
        const int row = m0 + ty * 4 + mi;
        float4 o0, o1;
        o0.x = acc[mi][0] + bias[0]; o0.y = acc[mi][1] + bias[1];
        o0.z = acc[mi][2] + bias[2]; o0.w = acc[mi][3] + bias[3];
        o1.x = acc[mi][4] + bias[4]; o1.y = acc[mi][5] + bias[5];
        o1.z = acc[mi][6] + bias[6]; o1.w = acc[mi][7] + bias[7];
        float* dst = gx + (long)row * G3 + n0 + tx * 8;
        *reinterpret_cast<float4*>(dst)     = o0;
        *reinterpret_cast<float4*>(dst + 4) = o1;
    }
}

// ---------------------------------------------------------------------------
// Kernel B v9: v8 + LDS-only barrier (gx prefetch survives the barrier) +
// rcp-based gates (no IEEE divide chains without -ffast-math).
// ---------------------------------------------------------------------------
__global__ __launch_bounds__(512, 1) void gru_mfma_kernel(
    const int* __restrict__ lengths, const float* __restrict__ w_hh,
    const float* __restrict__ b_hh, const float* __restrict__ h0,
    const float* __restrict__ gx, float* __restrict__ out)
{
    const int b0   = blockIdx.x * GROWS;
    const int tid  = threadIdx.x;
    const int lane = tid & 63;
    const int wv   = tid >> 6;          // 0..7
    const int frow = lane & 15;         // fragment row (A: batch m; B: dim n)
    const int fhi  = lane >> 4;         // 0..3 k-group
    const int dim  = wv * 16 + frow;    // this lane's hidden dim (0..127)

    __shared__ unsigned short hb[2][GROWS * D_];   // bf16 h, ping-pong, swizzled

    // ---- weight fragments: gate g, B rows g*128 + dim, loaded once ----
    bf16x8 wf[3][KT];
    #pragma unroll
    for (int g = 0; g < 3; ++g) {
        #pragma unroll
        for (int kt = 0; kt < KT; ++kt) {
            const float* wp = w_hh + (g * D_ + dim) * D_ + kt * 32 + fhi * 8;
            bf16x8 v;
            #pragma unroll
            for (int j = 0; j < 8; ++j) v[j] = (short)bf16_rne(wp[j]);
            wf[g][kt] = v;
        }
    }

    const float bhn_s = b_hh[2 * D_ + dim];   // n-gate bias, one scalar/lane

    // gate rows this lane owns: fhi*4 + r
    int   mylen[4];
    float hp[4];
    #pragma unroll
    for (int r = 0; r < 4; ++r) {
        int row = fhi * 4 + r;
        mylen[r] = lengths[b0 + row];
        hp[r]    = h0[(long)(b0 + row) * D_ + dim];
        int wb = (row * 256 + dim * 2) ^ ((row & 7) << 4);
        *(unsigned short*)((char*)hb[0] + wb) = bf16_rne(hp[r]);
    }
    const int lenmax = lengths[b0];     // lengths sorted descending
    __syncthreads();                    // once; full drain is fine here

    float* ys = out;
    float* hu = out + (long)B_ * S_ * D_;

    // ---- gx pipeline: cur holds step-s values, nxt prefetches s+1 ----
    float cur[3][4], nxt[3][4];
    #pragma unroll
    for (int g = 0; g < 3; ++g)
        #pragma unroll
        for (int r = 0; r < 4; ++r)
            cur[g][r] = gx[((long)(b0 + fhi * 4 + r) * S_ + 0) * G3 + g * 128 + dim];

    int pp = 0;
    for (int s = 0; s < lenmax; ++s) {
        // prefetch gx for s+1 — now survives the barrier (LDS-only sync)
        const int sn = (s + 1 < lenmax) ? s + 1 : lenmax - 1;
        #pragma unroll
        for (int g = 0; g < 3; ++g)
            #pragma unroll
            for (int r = 0; r < 4; ++r)
                nxt[g][r] = gx[((long)(b0 + fhi * 4 + r) * S_ + sn) * G3 + g * 128 + dim];

        // A-fragments of h (batch m = frow), swizzled LDS
        bf16x8 ah[KT];
        #pragma unroll
        for (int kt = 0; kt < KT; ++kt) {
            int ab = (frow * 256 + kt * 64 + fhi * 16) ^ ((frow & 7) << 4);
            ah[kt] = *(const bf16x8*)((const char*)hb[pp] + ab);
        }

        // 3 gate tiles: C col = dim, C row = batch
        f32x4 cr = {0.f,0.f,0.f,0.f}, cz = {0.f,0.f,0.f,0.f}, cn = {0.f,0.f,0.f,0.f};
        #pragma unroll
        for (int kt = 0; kt < KT; ++kt) {
            cr = __builtin_amdgcn_mfma_f32_16x16x32_bf16(ah[kt], wf[0][kt], cr, 0, 0, 0);
            cz = __builtin_amdgcn_mfma_f32_16x16x32_bf16(ah[kt], wf[1][kt], cz, 0, 0, 0);
            cn = __builtin_amdgcn_mfma_f32_16x16x32_bf16(ah[kt], wf[2][kt], cn, 0, 0, 0);
        }

        // gates fully in registers
        #pragma unroll
        for (int r = 0; r < 4; ++r) {
            const int row = fhi * 4 + r;
            const bool act = s < mylen[r];
            float rg = fsig(cur[0][r] + cr[r]);
            float zg = fsig(cur[1][r] + cz[r]);
            float ng = ftanh(cur[2][r] + rg * (cn[r] + bhn_s));
            float hn = (1.f - zg) * ng + zg * hp[r];
            if (act) {
                ys[((long)(b0 + row) * S_ + s) * D_ + dim] = hn;
                hp[r] = hn;
            }
            int wb = (row * 256 + dim * 2) ^ ((row & 7) << 4);
            *(unsigned short*)((char*)hb[pp ^ 1] + wb) = bf16_rne(hp[r]);
        }
        WG_SYNC_LDS();
        pp ^= 1;
        #pragma unroll
        for (int g = 0; g < 3; ++g)
            #pragma unroll
            for (int r = 0; r < 4; ++r)
                cur[g][r] = nxt[g][r];
    }

    // final hidden + zero tails
    #pragma unroll
    for (int r = 0; r < 4; ++r) {
        const int row = fhi * 4 + r;
        hu[(long)(b0 + row) * D_ + dim] = hp[r];
        for (int s = mylen[r]; s < S_; ++s)
            ys[((long)(b0 + row) * S_ + s) * D_ + dim] = 0.f;
    }
}

extern "C" void kernel_launch(void* const* d_in, const int* in_sizes, int n_in,
                              void* d_out, int out_size, void* d_ws, size_t ws_size,
                              hipStream_t stream) {
    const int*   items      = (const int*)d_in[0];
    const int*   basket_len = (const int*)d_in[1];
    const int*   lengths    = (const int*)d_in[2];
    const float* encode     = (const float*)d_in[3];
    const float* w_ih       = (const float*)d_in[4];
    const float* w_hh       = (const float*)d_in[5];
    const float* b_ih       = (const float*)d_in[6];
    const float* b_hh       = (const float*)d_in[7];
    const float* h0         = (const float*)d_in[8];
    float* out = (float*)d_out;

    float* gx     = (float*)d_ws;                       // 12800*384 f32 = 19.66 MB
    float* pooled = gx + (long)M_ * G3;                 // 12800*128 f32 =  6.55 MB

    pool_kernel<<<M_ / 2, 256, 0, stream>>>(
        items, basket_len, lengths, encode, pooled);
    gx_gemm_kernel<<<600, 256, 0, stream>>>(
        pooled, w_ih, b_ih, b_hh, gx);
    gru_mfma_kernel<<<B_ / GROWS, 512, 0, stream>>>(
        lengths, w_hh, b_hh, h0, gx, out);
}

// Round 19
// 110.297 us; speedup vs baseline: 1.5393x; 1.0253x over previous
//
#include <hip/hip_runtime.h>
#include <math.h>

#define B_ 256
#define S_ 50
#define K_ 20
#define D_ 128
#define G3 384          // 3*D
#define M_  (B_ * S_)   // 12800 (b,s) rows
#define GROWS 16        // batch rows per GRU block
#define KT 4            // k-tiles (32 wide): 128

typedef __attribute__((ext_vector_type(8))) short bf16x8;
typedef __attribute__((ext_vector_type(4))) float f32x4;

__device__ inline unsigned short bf16_rne(float f) {
    unsigned u = __float_as_uint(f);
    return (unsigned short)((u + 0x7fffu + ((u >> 16) & 1u)) >> 16);
}
__device__ inline float fsig(float x) {           // sigmoid, v_rcp (1ulp)
    return __builtin_amdgcn_rcpf(1.f + __expf(-x));
}
__device__ inline float ftanh(float x) {          // saturation-safe tanh, v_rcp
    float t = __expf(-2.f * fabsf(x));
    float r = (1.f - t) * __builtin_amdgcn_rcpf(1.f + t);
    return x >= 0.f ? r : -r;
}

// LDS-only workgroup barrier: drains ds ops (lgkmcnt) but leaves global
// loads/stores in flight across the barrier.
#define WG_SYNC_LDS() do { \
    __builtin_amdgcn_sched_barrier(0); \
    asm volatile("s_waitcnt lgkmcnt(0)" ::: "memory"); \
    __builtin_amdgcn_s_barrier(); \
    __builtin_amdgcn_sched_barrier(0); \
} while (0)

// ---------------------------------------------------------------------------
// Kernel P: basket pooling. 256 thr/block = two (b,s) rows; 6400 blocks.
// ---------------------------------------------------------------------------
__global__ __launch_bounds__(256) void pool_kernel(
    const int* __restrict__ items, const int* __restrict__ basket_len,
    const int* __restrict__ lengths, const float* __restrict__ encode,
    float* __restrict__ pooled)
{
    const int tid  = threadIdx.x;
    const int pair = tid >> 7;
    const int d    = tid & 127;
    const int m    = blockIdx.x * 2 + pair;
    const int b    = m / S_;
    const int s    = m % S_;
    const int len  = lengths[b];

    float p = 0.f;
    if (s < len) {
        const int  blen = basket_len[m];
        const int* it   = items + m * K_;
        for (int k = 0; k < blen; ++k)
            p += encode[(long)it[k] * D_ + d];
        p /= (float)blen;
    }
    pooled[m * D_ + d] = p;
}

// ---------------------------------------------------------------------------
// Kernel G: gx = pooled @ w_ih^T + b_ih (+ b_hh folded ONLY for r/z thirds).
// ---------------------------------------------------------------------------
__global__ __launch_bounds__(256) void gx_gemm_kernel(
    const float* __restrict__ pooled, const float* __restrict__ w_ih,
    const float* __restrict__ b_ih, const float* __restrict__ b_hh,
    float* __restrict__ gx)
{
    __shared__ float As[32][64];    // [k][m]
    __shared__ float Bs[32][128];   // [k][n]

    const int tid = threadIdx.x;
    const int bm  = blockIdx.x % 200;
    const int bn  = blockIdx.x / 200;
    const int m0  = bm * 64;
    const int n0  = bn * 128;
    const int tx  = tid & 15;               // -> N
    const int ty  = tid >> 4;               // -> M

    float acc[4][8] = {};

    for (int kt = 0; kt < 128; kt += 32) {
        #pragma unroll
        for (int i = 0; i < 2; ++i) {
            int idx = tid + 256 * i;
            int r = idx >> 3, c = idx & 7;
            float4 v = *reinterpret_cast<const float4*>(
                pooled + (m0 + r) * 128 + kt + c * 4);
            As[c*4+0][r] = v.x; As[c*4+1][r] = v.y;
            As[c*4+2][r] = v.z; As[c*4+3][r] = v.w;
        }
        #pragma unroll
        for (int i = 0; i < 4; ++i) {
            int idx = tid + 256 * i;
            int r = idx >> 3, c = idx & 7;
            float4 v = *reinterpret_cast<const float4*>(
                w_ih + (n0 + r) * 128 + kt + c * 4);
            Bs[c*4+0][r] = v.x; Bs[c*4+1][r] = v.y;
            Bs[c*4+2][r] = v.z; Bs[c*4+3][r] = v.w;
        }
        __syncthreads();

        #pragma unroll
        for (int k = 0; k < 32; ++k) {
            float4 a  = *reinterpret_cast<const float4*>(&As[k][ty * 4]);
            float4 b0 = *reinterpret_cast<const float4*>(&Bs[k][tx * 8]);
            float4 b1 = *reinterpret_cast<const float4*>(&Bs[k][tx * 8 + 4]);
            float av[4] = {a.x, a.y, a.z, a.w};
            float bv[8] = {b0.x, b0.y, b0.z, b0.w, b1.x, b1.y, b1.z, b1.w};
            #pragma unroll
            for (int mi = 0; mi < 4; ++mi)
                #pragma unroll
                for (int ni = 0; ni < 8; ++ni)
                    acc[mi][ni] = fmaf(av[mi], bv[ni], acc[mi][ni]);
        }
        __syncthreads();
    }

    float bias[8];
    #pragma unroll
    for (int ni = 0; ni < 8; ++ni) {
        int n = n0 + tx * 8 + ni;
        bias[ni] = b_ih[n] + (n < 2 * D_ ? b_hh[n] : 0.f);   // fold r/z only
    }
    #pragma unroll
    for (int mi = 0; mi < 4; ++mi) {
        const int row = m0 + ty * 4 + mi;
        float4 o0, o1;
        o0.x = acc[mi][0] + bias[0]; o0.y = acc[mi][1] + bias[1];
        o0.z = acc[mi][2] + bias[2]; o0.w = acc[mi][3] + bias[3];
        o1.x = acc[mi][4] + bias[4]; o1.y = acc[mi][5] + bias[5];
        o1.z = acc[mi][6] + bias[6]; o1.w = acc[mi][7] + bias[7];
        float* dst = gx + (long)row * G3 + n0 + tx * 8;
        *reinterpret_cast<float4*>(dst)     = o0;
        *reinterpret_cast<float4*>(dst + 4) = o1;
    }
}

// ---------------------------------------------------------------------------
// Kernel B v10: v9 + 2-step unroll with alternating NAMED gx buffers.
// R18 diagnosis: the `cur = nxt` register copy forced s_waitcnt vmcnt right
// after the barrier -> gx L3 latency (~500-900cyc) exposed every step. With
// named curA/curB alternation there is no copy; first USE of the prefetched
// regs is next step's gate phase (after ds_read + 12 MFMA = full cover).
// ---------------------------------------------------------------------------
__global__ __launch_bounds__(512, 1) void gru_mfma_kernel(
    const int* __restrict__ lengths, const float* __restrict__ w_hh,
    const float* __restrict__ b_hh, const float* __restrict__ h0,
    const float* __restrict__ gx, float* __restrict__ out)
{
    const int b0   = blockIdx.x * GROWS;
    const int tid  = threadIdx.x;
    const int lane = tid & 63;
    const int wv   = tid >> 6;          // 0..7
    const int frow = lane & 15;         // fragment row (A: batch m; B: dim n)
    const int fhi  = lane >> 4;         // 0..3 k-group
    const int dim  = wv * 16 + frow;    // this lane's hidden dim (0..127)

    __shared__ unsigned short hb[2][GROWS * D_];   // bf16 h, ping-pong, swizzled

    // ---- weight fragments: gate g, B rows g*128 + dim, loaded once ----
    bf16x8 wf[3][KT];
    #pragma unroll
    for (int g = 0; g < 3; ++g) {
        #pragma unroll
        for (int kt = 0; kt < KT; ++kt) {
            const float* wp = w_hh + (g * D_ + dim) * D_ + kt * 32 + fhi * 8;
            bf16x8 v;
            #pragma unroll
            for (int j = 0; j < 8; ++j) v[j] = (short)bf16_rne(wp[j]);
            wf[g][kt] = v;
        }
    }

    const float bhn_s = b_hh[2 * D_ + dim];   // n-gate bias, one scalar/lane

    int   mylen[4];
    float hp[4];
    #pragma unroll
    for (int r = 0; r < 4; ++r) {
        int row = fhi * 4 + r;
        mylen[r] = lengths[b0 + row];
        hp[r]    = h0[(long)(b0 + row) * D_ + dim];
        int wb = (row * 256 + dim * 2) ^ ((row & 7) << 4);
        *(unsigned short*)((char*)hb[0] + wb) = bf16_rne(hp[r]);
    }
    const int lenmax = lengths[b0];     // lengths sorted descending
    __syncthreads();

    float* ys = out;
    float* hu = out + (long)B_ * S_ * D_;

    const long gxrow[4] = {
        (long)(b0 + fhi * 4 + 0) * S_, (long)(b0 + fhi * 4 + 1) * S_,
        (long)(b0 + fhi * 4 + 2) * S_, (long)(b0 + fhi * 4 + 3) * S_ };

    // step body: uses CUR gx regs, prefetches NXT for step sn, h from hb[PP]
    #define GSTEP(s, CUR, NXT, PP) { \
        const int sn = ((s) + 1 < lenmax) ? (s) + 1 : lenmax - 1; \
        _Pragma("unroll") \
        for (int g = 0; g < 3; ++g) \
            _Pragma("unroll") \
            for (int r = 0; r < 4; ++r) \
                NXT[g][r] = gx[(gxrow[r] + sn) * G3 + g * 128 + dim]; \
        bf16x8 ah[KT]; \
        _Pragma("unroll") \
        for (int kt = 0; kt < KT; ++kt) { \
            int ab = (frow * 256 + kt * 64 + fhi * 16) ^ ((frow & 7) << 4); \
            ah[kt] = *(const bf16x8*)((const char*)hb[PP] + ab); \
        } \
        f32x4 cr = {0.f,0.f,0.f,0.f}, cz = {0.f,0.f,0.f,0.f}, cn = {0.f,0.f,0.f,0.f}; \
        _Pragma("unroll") \
        for (int kt = 0; kt < KT; ++kt) { \
            cr = __builtin_amdgcn_mfma_f32_16x16x32_bf16(ah[kt], wf[0][kt], cr, 0, 0, 0); \
            cz = __builtin_amdgcn_mfma_f32_16x16x32_bf16(ah[kt], wf[1][kt], cz, 0, 0, 0); \
            cn = __builtin_amdgcn_mfma_f32_16x16x32_bf16(ah[kt], wf[2][kt], cn, 0, 0, 0); \
        } \
        _Pragma("unroll") \
        for (int r = 0; r < 4; ++r) { \
            const int row = fhi * 4 + r; \
            const bool act = (s) < mylen[r]; \
            float rg = fsig(CUR[0][r] + cr[r]); \
            float zg = fsig(CUR[1][r] + cz[r]); \
            float ng = ftanh(CUR[2][r] + rg * (cn[r] + bhn_s)); \
            float hn = (1.f - zg) * ng + zg * hp[r]; \
            if (act) { \
                ys[(gxrow[r] + (s)) * D_ + dim] = hn; \
                hp[r] = hn; \
            } \
            int wb = (row * 256 + dim * 2) ^ ((row & 7) << 4); \
            *(unsigned short*)((char*)hb[(PP) ^ 1] + wb) = bf16_rne(hp[r]); \
        } \
        WG_SYNC_LDS(); \
    }

    float curA[3][4], curB[3][4];
    #pragma unroll
    for (int g = 0; g < 3; ++g)
        #pragma unroll
        for (int r = 0; r < 4; ++r)
            curA[g][r] = gx[(gxrow[r] + 0) * G3 + g * 128 + dim];

    int s = 0, pp = 0;
    while (s < lenmax) {
        GSTEP(s, curA, curB, pp);
        ++s; pp ^= 1;
        if (s >= lenmax) break;
        GSTEP(s, curB, curA, pp);
        ++s; pp ^= 1;
    }
    #undef GSTEP

    // final hidden + zero tails
    #pragma unroll
    for (int r = 0; r < 4; ++r) {
        const int row = fhi * 4 + r;
        hu[(long)(b0 + row) * D_ + dim] = hp[r];
        for (int t = mylen[r]; t < S_; ++t)
            ys[((long)(b0 + row) * S_ + t) * D_ + dim] = 0.f;
    }
}

extern "C" void kernel_launch(void* const* d_in, const int* in_sizes, int n_in,
                              void* d_out, int out_size, void* d_ws, size_t ws_size,
                              hipStream_t stream) {
    const int*   items      = (const int*)d_in[0];
    const int*   basket_len = (const int*)d_in[1];
    const int*   lengths    = (const int*)d_in[2];
    const float* encode     = (const float*)d_in[3];
    const float* w_ih       = (const float*)d_in[4];
    const float* w_hh       = (const float*)d_in[5];
    const float* b_ih       = (const float*)d_in[6];
    const float* b_hh       = (const float*)d_in[7];
    const float* h0         = (const float*)d_in[8];
    float* out = (float*)d_out;

    float* gx     = (float*)d_ws;                       // 12800*384 f32 = 19.66 MB
    float* pooled = gx + (long)M_ * G3;                 // 12800*128 f32 =  6.55 MB

    pool_kernel<<<M_ / 2, 256, 0, stream>>>(
        items, basket_len, lengths, encode, pooled);
    gx_gemm_kernel<<<600, 256, 0, stream>>>(
        pooled, w_ih, b_ih, b_hh, gx);
    gru_mfma_kernel<<<B_ / GROWS, 512, 0, stream>>>(
        lengths, w_hh, b_hh, h0, gx, out);
}

// Round 20
// 94.239 us; speedup vs baseline: 1.8016x; 1.1704x over previous
//
#include <hip/hip_runtime.h>
#include <math.h>

#define B_ 256
#define S_ 50
#define K_ 20
#define D_ 128
#define G3 384          // 3*D
#define M_  (B_ * S_)   // 12800 (b,s) rows
#define GROWS 16        // batch rows per GRU block
#define KT 4            // k-tiles (32 wide): 128

typedef __attribute__((ext_vector_type(8))) short bf16x8;
typedef __attribute__((ext_vector_type(4))) float f32x4;

__device__ inline unsigned short bf16_rne(float f) {
    unsigned u = __float_as_uint(f);
    return (unsigned short)((u + 0x7fffu + ((u >> 16) & 1u)) >> 16);
}
__device__ inline float fsig(float x) {
    return __builtin_amdgcn_rcpf(1.f + __expf(-x));
}
__device__ inline float ftanh(float x) {
    float t = __expf(-2.f * fabsf(x));
    float r = (1.f - t) * __builtin_amdgcn_rcpf(1.f + t);
    return x >= 0.f ? r : -r;
}

#define WG_SYNC_LDS() do { \
    __builtin_amdgcn_sched_barrier(0); \
    asm volatile("s_waitcnt lgkmcnt(0)" ::: "memory"); \
    __builtin_amdgcn_s_barrier(); \
    __builtin_amdgcn_sched_barrier(0); \
} while (0)

// ---------------------------------------------------------------------------
// Kernel P: basket pooling -> bf16 output (feeds the MFMA gemm directly).
// ---------------------------------------------------------------------------
__global__ __launch_bounds__(256) void pool_kernel(
    const int* __restrict__ items, const int* __restrict__ basket_len,
    const int* __restrict__ lengths, const float* __restrict__ encode,
    unsigned short* __restrict__ pooled_bf)
{
    const int tid  = threadIdx.x;
    const int pair = tid >> 7;
    const int d    = tid & 127;
    const int m    = blockIdx.x * 2 + pair;
    const int b    = m / S_;
    const int s    = m % S_;
    const int len  = lengths[b];

    float p = 0.f;
    if (s < len) {
        const int  blen = basket_len[m];
        const int* it   = items + m * K_;
        for (int k = 0; k < blen; ++k)
            p += encode[(long)it[k] * D_ + d];
        p /= (float)blen;
    }
    pooled_bf[m * D_ + d] = bf16_rne(p);
}

// ---------------------------------------------------------------------------
// Kernel W: w_ih f32 -> bf16 (one-time, 49152 elems).
// ---------------------------------------------------------------------------
__global__ __launch_bounds__(256) void wih_cvt_kernel(
    const float* __restrict__ w_ih, unsigned short* __restrict__ wih_bf)
{
    int i = blockIdx.x * 256 + threadIdx.x;
    if (i < G3 * D_) wih_bf[i] = bf16_rne(w_ih[i]);
}

// ---------------------------------------------------------------------------
// Kernel G v2: MFMA GEMM. gx = pooled @ w_ih^T + b_ih (+b_hh for r/z).
// M=12800, N=384, K=128. 128x128 block tile, 4 waves (each 64x64), single
// K stage (whole K=128 in LDS), XOR-swizzled [row][k] bf16 tiles (T2).
// Replaces the f32 vector GEMM (4096 fmaf/thread -> 64 MFMA/wave).
// ---------------------------------------------------------------------------
__global__ __launch_bounds__(256) void gx_gemm_mfma(
    const unsigned short* __restrict__ pooled_bf,
    const unsigned short* __restrict__ wih_bf,
    const float* __restrict__ b_ih, const float* __restrict__ b_hh,
    float* __restrict__ gx)
{
    __shared__ unsigned short Al[128 * 128];   // [m][k] swizzled, 32KB
    __shared__ unsigned short Bl[128 * 128];   // [n][k] swizzled, 32KB

    const int tid  = threadIdx.x;
    const int bm   = blockIdx.x % 100;
    const int bn   = blockIdx.x / 100;         // 0..2
    const int m0   = bm * 128;
    const int n0   = bn * 128;
    const int lane = tid & 63;
    const int wv   = tid >> 6;                 // 0..3
    const int frow = lane & 15;
    const int fhi  = lane >> 4;
    const int mh   = (wv & 1) * 64;
    const int nh   = (wv >> 1) * 64;

    // stage A and B: 128 rows x 256B each; 16B/thread x 8 iters
    #pragma unroll
    for (int i = 0; i < 8; ++i) {
        int idx = tid + i * 256;               // 0..2047
        int row = idx >> 4, c16 = idx & 15;
        int dst = (row * 256 + c16 * 16) ^ ((row & 7) << 4);
        *(bf16x8*)((char*)Al + dst) =
            *(const bf16x8*)(pooled_bf + (long)(m0 + row) * D_ + c16 * 8);
        *(bf16x8*)((char*)Bl + dst) =
            *(const bf16x8*)(wih_bf + (long)(n0 + row) * D_ + c16 * 8);
    }
    __syncthreads();

    // fragments
    bf16x8 af[4][KT], bf[4][KT];
    #pragma unroll
    for (int t = 0; t < 4; ++t) {
        #pragma unroll
        for (int kt = 0; kt < KT; ++kt) {
            int ra = mh + t * 16 + frow;
            int oa = (ra * 256 + kt * 64 + fhi * 16) ^ ((ra & 7) << 4);
            af[t][kt] = *(const bf16x8*)((const char*)Al + oa);
            int rb = nh + t * 16 + frow;
            int ob = (rb * 256 + kt * 64 + fhi * 16) ^ ((rb & 7) << 4);
            bf[t][kt] = *(const bf16x8*)((const char*)Bl + ob);
        }
    }

    f32x4 acc[4][4];
    #pragma unroll
    for (int mt = 0; mt < 4; ++mt)
        #pragma unroll
        for (int nt = 0; nt < 4; ++nt) {
            f32x4 c = {0.f, 0.f, 0.f, 0.f};
            #pragma unroll
            for (int kt = 0; kt < KT; ++kt)
                c = __builtin_amdgcn_mfma_f32_16x16x32_bf16(af[mt][kt], bf[nt][kt], c, 0, 0, 0);
            acc[mt][nt] = c;
        }

    // bias per nt (n = n0+nh+nt*16+frow), fold b_hh for r/z thirds only
    float bias[4];
    #pragma unroll
    for (int nt = 0; nt < 4; ++nt) {
        int n = n0 + nh + nt * 16 + frow;
        bias[nt] = b_ih[n] + (n < 2 * D_ ? b_hh[n] : 0.f);
    }

    // epilogue: C col = n (frow), row = fhi*4 + reg
    #pragma unroll
    for (int mt = 0; mt < 4; ++mt) {
        #pragma unroll
        for (int nt = 0; nt < 4; ++nt) {
            int n = n0 + nh + nt * 16 + frow;
            #pragma unroll
            for (int r = 0; r < 4; ++r) {
                int row = m0 + mh + mt * 16 + fhi * 4 + r;
                gx[(long)row * G3 + n] = acc[mt][nt][r] + bias[nt];
            }
        }
    }
}

// ---------------------------------------------------------------------------
// Kernel B v11: v10 + distance-2 gx prefetch (triple named buffers).
// Diagnostic: if gru drops, load latency was exposed; if flat, step cost is
// issue-pressure (next lever: fewer instructions/step).
// ---------------------------------------------------------------------------
__global__ __launch_bounds__(512, 1) void gru_mfma_kernel(
    const int* __restrict__ lengths, const float* __restrict__ w_hh,
    const float* __restrict__ b_hh, const float* __restrict__ h0,
    const float* __restrict__ gx, float* __restrict__ out)
{
    const int b0   = blockIdx.x * GROWS;
    const int tid  = threadIdx.x;
    const int lane = tid & 63;
    const int wv   = tid >> 6;
    const int frow = lane & 15;
    const int fhi  = lane >> 4;
    const int dim  = wv * 16 + frow;

    __shared__ unsigned short hb[2][GROWS * D_];

    bf16x8 wf[3][KT];
    #pragma unroll
    for (int g = 0; g < 3; ++g) {
        #pragma unroll
        for (int kt = 0; kt < KT; ++kt) {
            const float* wp = w_hh + (g * D_ + dim) * D_ + kt * 32 + fhi * 8;
            bf16x8 v;
            #pragma unroll
            for (int j = 0; j < 8; ++j) v[j] = (short)bf16_rne(wp[j]);
            wf[g][kt] = v;
        }
    }

    const float bhn_s = b_hh[2 * D_ + dim];

    int   mylen[4];
    float hp[4];
    #pragma unroll
    for (int r = 0; r < 4; ++r) {
        int row = fhi * 4 + r;
        mylen[r] = lengths[b0 + row];
        hp[r]    = h0[(long)(b0 + row) * D_ + dim];
        int wb = (row * 256 + dim * 2) ^ ((row & 7) << 4);
        *(unsigned short*)((char*)hb[0] + wb) = bf16_rne(hp[r]);
    }
    const int lenmax = lengths[b0];
    __syncthreads();

    float* ys = out;
    float* hu = out + (long)B_ * S_ * D_;

    const long gxrow[4] = {
        (long)(b0 + fhi * 4 + 0) * S_, (long)(b0 + fhi * 4 + 1) * S_,
        (long)(b0 + fhi * 4 + 2) * S_, (long)(b0 + fhi * 4 + 3) * S_ };

    // step body: uses CUR, prefetches step s+2 into NXT
    #define GSTEP(s, CUR, NXT, PP) { \
        const int sn = ((s) + 2 < lenmax) ? (s) + 2 : lenmax - 1; \
        _Pragma("unroll") \
        for (int g = 0; g < 3; ++g) \
            _Pragma("unroll") \
            for (int r = 0; r < 4; ++r) \
                NXT[g][r] = gx[(gxrow[r] + sn) * G3 + g * 128 + dim]; \
        bf16x8 ah[KT]; \
        _Pragma("unroll") \
        for (int kt = 0; kt < KT; ++kt) { \
            int ab = (frow * 256 + kt * 64 + fhi * 16) ^ ((frow & 7) << 4); \
            ah[kt] = *(const bf16x8*)((const char*)hb[PP] + ab); \
        } \
        f32x4 cr = {0.f,0.f,0.f,0.f}, cz = {0.f,0.f,0.f,0.f}, cn = {0.f,0.f,0.f,0.f}; \
        _Pragma("unroll") \
        for (int kt = 0; kt < KT; ++kt) { \
            cr = __builtin_amdgcn_mfma_f32_16x16x32_bf16(ah[kt], wf[0][kt], cr, 0, 0, 0); \
            cz = __builtin_amdgcn_mfma_f32_16x16x32_bf16(ah[kt], wf[1][kt], cz, 0, 0, 0); \
            cn = __builtin_amdgcn_mfma_f32_16x16x32_bf16(ah[kt], wf[2][kt], cn, 0, 0, 0); \
        } \
        _Pragma("unroll") \
        for (int r = 0; r < 4; ++r) { \
            const int row = fhi * 4 + r; \
            const bool act = (s) < mylen[r]; \
            float rg = fsig(CUR[0][r] + cr[r]); \
            float zg = fsig(CUR[1][r] + cz[r]); \
            float ng = ftanh(CUR[2][r] + rg * (cn[r] + bhn_s)); \
            float hn = (1.f - zg) * ng + zg * hp[r]; \
            if (act) { \
                ys[(gxrow[r] + (s)) * D_ + dim] = hn; \
                hp[r] = hn; \
            } \
            int wb = (row * 256 + dim * 2) ^ ((row & 7) << 4); \
            *(unsigned short*)((char*)hb[(PP) ^ 1] + wb) = bf16_rne(hp[r]); \
        } \
        WG_SYNC_LDS(); \
    }

    float curA[3][4], curB[3][4], curC[3][4];
    const int s1 = (1 < lenmax) ? 1 : 0;
    #pragma unroll
    for (int g = 0; g < 3; ++g)
        #pragma unroll
        for (int r = 0; r < 4; ++r) {
            curA[g][r] = gx[(gxrow[r] + 0) * G3 + g * 128 + dim];
            curB[g][r] = gx[(gxrow[r] + s1) * G3 + g * 128 + dim];
        }

    int s = 0, pp = 0;
    while (s < lenmax) {
        GSTEP(s, curA, curC, pp);
        ++s; pp ^= 1;
        if (s >= lenmax) break;
        GSTEP(s, curB, curA, pp);
        ++s; pp ^= 1;
        if (s >= lenmax) break;
        GSTEP(s, curC, curB, pp);
        ++s; pp ^= 1;
    }
    #undef GSTEP

    #pragma unroll
    for (int r = 0; r < 4; ++r) {
        const int row = fhi * 4 + r;
        hu[(long)(b0 + row) * D_ + dim] = hp[r];
        for (int t = mylen[r]; t < S_; ++t)
            ys[((long)(b0 + row) * S_ + t) * D_ + dim] = 0.f;
    }
}

extern "C" void kernel_launch(void* const* d_in, const int* in_sizes, int n_in,
                              void* d_out, int out_size, void* d_ws, size_t ws_size,
                              hipStream_t stream) {
    const int*   items      = (const int*)d_in[0];
    const int*   basket_len = (const int*)d_in[1];
    const int*   lengths    = (const int*)d_in[2];
    const float* encode     = (const float*)d_in[3];
    const float* w_ih       = (const float*)d_in[4];
    const float* w_hh       = (const float*)d_in[5];
    const float* b_ih       = (const float*)d_in[6];
    const float* b_hh       = (const float*)d_in[7];
    const float* h0         = (const float*)d_in[8];
    float* out = (float*)d_out;

    float*          gx        = (float*)d_ws;                    // 19.66 MB
    unsigned short* pooled_bf = (unsigned short*)(gx + (long)M_ * G3);  // 3.28 MB
    unsigned short* wih_bf    = pooled_bf + (long)M_ * D_;       // 96 KB

    pool_kernel<<<M_ / 2, 256, 0, stream>>>(
        items, basket_len, lengths, encode, pooled_bf);
    wih_cvt_kernel<<<(G3 * D_ + 255) / 256, 256, 0, stream>>>(w_ih, wih_bf);
    gx_gemm_mfma<<<300, 256, 0, stream>>>(
        pooled_bf, wih_bf, b_ih, b_hh, gx);
    gru_mfma_kernel<<<B_ / GROWS, 512, 0, stream>>>(
        lengths, w_hh, b_hh, h0, gx, out);
}